// Round 1
// baseline (258.449 us; speedup 1.0000x reference)
//
#include <hip/hip_runtime.h>

// PatchShift: out[b,t,h,w,c] = x[b, (t - S[h%3][w%3]) % T, h, w, c]
// B=32, T=8, H=W=14, C=768, fp32.
// Pure permutation along T => memory-bound coalesced copy.
//
// Layout strides (in float4 units, C4 = 768/4 = 192):
//   row id = ((b*T + t)*H + h)*W + w   (50176 rows, 192 float4 each)
//
// One 64-lane wave handles one row: row math is wave-uniform (scalarized),
// lanes do 3 coalesced float4 load/store pairs (192 = 3*64).

#define NB       32
#define NT       8
#define NH       14
#define NW       14
#define C4       192            // 768 floats / 4
#define NROWS    (NB * NT * NH * NW)   // 50176
#define ROWS_PER_BLOCK 4               // 4 waves per 256-thread block

__global__ __launch_bounds__(256)
void patch_shift_kernel(const float4* __restrict__ x, float4* __restrict__ out) {
    const int wave = threadIdx.x >> 6;   // 0..3
    const int lane = threadIdx.x & 63;

    const int row = blockIdx.x * ROWS_PER_BLOCK + wave;   // exact cover, no guard needed
    // Decompose row -> (bt, h, w); all wave-uniform.
    const int hw = row % (NH * NW);      // 0..195
    const int bt = row / (NH * NW);      // b*8 + t
    const int t  = bt & (NT - 1);
    const int h  = hw / NW;
    const int w  = hw % NW;

    // shift_table[h%3][w%3] = {{-4,1,2},{-1,0,3},{-2,-3,4}}
    // packed nibbles: value+4 at nibble index (h%3)*3 + (w%3)
    const unsigned long long packed = 0x812743650ull;
    const int idx = (h % 3) * 3 + (w % 3);
    const int s = (int)((packed >> (idx * 4)) & 0xF) - 4;

    const int st = (t - s + 8) & (NT - 1);        // (t - S) mod 8
    const int src_row = (bt - t + st) * (NH * NW) + hw;

    const float4* src = x   + (long long)src_row * C4;
    float4*       dst = out + (long long)row     * C4;

    #pragma unroll
    for (int k = 0; k < 3; ++k) {
        dst[k * 64 + lane] = src[k * 64 + lane];
    }
}

extern "C" void kernel_launch(void* const* d_in, const int* in_sizes, int n_in,
                              void* d_out, int out_size, void* d_ws, size_t ws_size,
                              hipStream_t stream) {
    const float4* x   = (const float4*)d_in[0];
    float4*       out = (float4*)d_out;

    const int grid = NROWS / ROWS_PER_BLOCK;   // 12544
    patch_shift_kernel<<<grid, 256, 0, stream>>>(x, out);
}